// Round 1
// baseline (31445.657 us; speedup 1.0000x reference)
//
#include <hip/hip_runtime.h>
#include <math.h>

#define NB 256   // batch
#define NN 256   // N (code length)
#define NK 128   // K (info bits)
#define ND 256   // D (embedding dim)
#define NH 512   // H (hidden dim)

// output layout (floats) in d_out, reference return order:
#define OUT_X 0
#define OUT_F 65536
#define OUT_U 131072
#define OUT_P 196608

#define EPB (255 * ND)  // E floats per batch (levels 1..8: 128+64+...+1 = 255 positions)
#define LPB 255         // partial-sum bits per batch

// position offset of level d (d in 1..8) within the per-batch E/L slabs
__device__ __forceinline__ int loff(int d) { return 256 - (1 << (9 - d)); }

// One MLP stage for the current node: P output positions, input gathered as
// [E_d[2p], E_d[2p+1], (bn only) label_emb[h1[p]]].  256 threads.
// GEMM1: thread owns hidden pair (2t,2t+1).  GEMM2: thread owns out col t.
template <int PC, int KIN>
__device__ __forceinline__ void mlp_stage(
    int P,
    const float* __restrict__ Esrc,   // nullptr => root (obs_emb[2] broadcast)
    float* __restrict__ Edst,
    const int* __restrict__ h1bits,   // used when KIN==768
    const float* __restrict__ obs2, const float* __restrict__ lemb,
    const float* __restrict__ W1, const float* __restrict__ b1,
    const float* __restrict__ W2, const float* __restrict__ b2,
    float* inS, float* hidS, int tid)
{
  for (int p0 = 0; p0 < P; p0 += PC) {
    // ---- stage input rows into LDS (coalesced gather) ----
#pragma unroll
    for (int p = 0; p < PC; ++p) {
      const int pos = p0 + p;
      for (int k = tid; k < KIN; k += 256) {
        float v;
        if (KIN == 768 && k >= 512) {
          v = lemb[h1bits[pos] * ND + (k - 512)];
        } else {
          const int col = k & 255;
          v = Esrc ? Esrc[(2 * pos + ((k >> 8) & 1)) * ND + col] : obs2[col];
        }
        inS[p * KIN + k] = v;
      }
    }
    __syncthreads();

    // ---- GEMM1: hidden = relu(in @ W1 + b1) ----
    float acc0[PC], acc1[PC];
#pragma unroll
    for (int p = 0; p < PC; ++p) { acc0[p] = 0.f; acc1[p] = 0.f; }
#pragma unroll 2
    for (int k = 0; k < KIN; k += 2) {
      const float2 wA = *(const float2*)&W1[(size_t)k * NH + 2 * tid];
      const float2 wB = *(const float2*)&W1[(size_t)(k + 1) * NH + 2 * tid];
#pragma unroll
      for (int p = 0; p < PC; ++p) {
        const float2 iv = *(const float2*)&inS[p * KIN + k];
        acc0[p] += iv.x * wA.x + iv.y * wB.x;
        acc1[p] += iv.x * wA.y + iv.y * wB.y;
      }
    }
    const float bb0 = b1[2 * tid], bb1 = b1[2 * tid + 1];
#pragma unroll
    for (int p = 0; p < PC; ++p) {
      float h0 = acc0[p] + bb0; h0 = h0 > 0.f ? h0 : 0.f;
      float h1 = acc1[p] + bb1; h1 = h1 > 0.f ? h1 : 0.f;
      *(float2*)&hidS[p * NH + 2 * tid] = make_float2(h0, h1);
    }
    __syncthreads();

    // ---- GEMM2: out = hidden @ W2 + b2 ----
    float acc2[PC];
#pragma unroll
    for (int p = 0; p < PC; ++p) acc2[p] = 0.f;
#pragma unroll 2
    for (int h = 0; h < NH; h += 2) {
      const float w0 = W2[(size_t)h * ND + tid];
      const float w1 = W2[(size_t)(h + 1) * ND + tid];
#pragma unroll
      for (int p = 0; p < PC; ++p) {
        const float2 hv = *(const float2*)&hidS[p * NH + h];
        acc2[p] += hv.x * w0 + hv.y * w1;
      }
    }
    const float bo = b2[tid];
#pragma unroll
    for (int p = 0; p < PC; ++p) Edst[(p0 + p) * ND + tid] = acc2[p] + bo;
    __syncthreads();
  }
}

__global__ __launch_bounds__(256, 1) void sc_monolith(
    const int* __restrict__ info_bits, const float* __restrict__ rv,
    const int* __restrict__ info_set,
    const float* __restrict__ obs_emb, const float* __restrict__ label_emb,
    const float* __restrict__ cnW1, const float* __restrict__ cnb1,
    const float* __restrict__ cnW2, const float* __restrict__ cnb2,
    const float* __restrict__ bnW1, const float* __restrict__ bnb1,
    const float* __restrict__ bnW2, const float* __restrict__ bnb2,
    const float* __restrict__ llrW, const float* __restrict__ llrb,
    float* __restrict__ out, float* __restrict__ Ebuf, int* __restrict__ Lbuf)
{
  __shared__ float inS[8 * 768];   // 24 KB
  __shared__ float hidS[8 * 512];  // 16 KB
  __shared__ int curS0[256], nxtS0[256];
  __shared__ float red[512];

  const int tid = threadIdx.x;
  const int b = blockIdx.x;
  float* E = Ebuf + (size_t)b * EPB;
  int* L = Lbuf + (size_t)b * LPB;
  const float* obs2 = obs_emb + 2 * ND;

  // cn descent at depth d: E_d -> E_{d+1}
  auto cn = [&](int d) {
    const float* src = (d == 0) ? nullptr : (E + loff(d) * ND);
    float* dst = E + loff(d + 1) * ND;
    const int P = 1 << (7 - d);
    switch (d) {
      case 0: case 1: case 2: case 3: case 4:
        mlp_stage<8, 512>(P, src, dst, nullptr, obs2, label_emb, cnW1, cnb1, cnW2, cnb2, inS, hidS, tid); break;
      case 5:
        mlp_stage<4, 512>(P, src, dst, nullptr, obs2, label_emb, cnW1, cnb1, cnW2, cnb2, inS, hidS, tid); break;
      case 6:
        mlp_stage<2, 512>(P, src, dst, nullptr, obs2, label_emb, cnW1, cnb1, cnW2, cnb2, inS, hidS, tid); break;
      default:
        mlp_stage<1, 512>(P, src, dst, nullptr, obs2, label_emb, cnW1, cnb1, cnW2, cnb2, inS, hidS, tid); break;
    }
  };
  // bn descent at depth d (right child): uses left-child bits L_{d+1}
  auto bn = [&](int d) {
    const float* src = (d == 0) ? nullptr : (E + loff(d) * ND);
    float* dst = E + loff(d + 1) * ND;
    const int* h1 = L + loff(d + 1);
    const int P = 1 << (7 - d);
    switch (d) {
      case 0: case 1: case 2: case 3: case 4:
        mlp_stage<8, 768>(P, src, dst, h1, obs2, label_emb, bnW1, bnb1, bnW2, bnb2, inS, hidS, tid); break;
      case 5:
        mlp_stage<4, 768>(P, src, dst, h1, obs2, label_emb, bnW1, bnb1, bnW2, bnb2, inS, hidS, tid); break;
      case 6:
        mlp_stage<2, 768>(P, src, dst, h1, obs2, label_emb, bnW1, bnb1, bnW2, bnb2, inS, hidS, tid); break;
      default:
        mlp_stage<1, 768>(P, src, dst, h1, obs2, label_emb, bnW1, bnb1, bnW2, bnb2, inS, hidS, tid); break;
    }
  };

  auto leaf = [&](int off) {
    const float* E8 = E + loff(8) * ND;
    // logits = e @ llr_W + llr_b via block reduction
    const float ev = E8[tid];
    red[tid] = ev * llrW[2 * tid];
    red[256 + tid] = ev * llrW[2 * tid + 1];
    __syncthreads();
    for (int s = 128; s > 0; s >>= 1) {
      if (tid < s) { red[tid] += red[tid + s]; red[256 + tid] += red[256 + tid + s]; }
      __syncthreads();
    }
    const float l0 = red[0] + llrb[0];
    const float l1 = red[256] + llrb[1];
    const float m = fmaxf(l0, l1);
    const float e0 = expf(l0 - m), e1 = expf(l1 - m);
    const float s = e0 + e1;
    const float p0 = e0 / s, p1 = e1 / s;
    const int hard = (rv[b * NN + off] > p0) ? 1 : 0;
    // binary search off in info_set (sorted)
    int lo = 0, hi = NK;
    while (lo < hi) { const int mid = (lo + hi) >> 1; if (info_set[mid] < off) lo = mid + 1; else hi = mid; }
    const int fidx = (lo < NK && info_set[lo] == off) ? lo : -1;
    const int fval = (fidx >= 0) ? info_bits[b * NK + fidx] : 2;
    const int xb = (fval == 2) ? hard : fval;
    if (tid == 0) {
      out[OUT_F + b * NN + off] = (fidx >= 0) ? 2.0f : (float)xb;
      out[OUT_U + b * NN + off] = (float)xb;
      out[OUT_P + (b * NN + off) * 2 + 0] = p0;
      out[OUT_P + (b * NN + off) * 2 + 1] = p1;
      curS0[0] = xb;
    }
    __syncthreads();
    // merge cascade: parent[2i] = left[i]^right[i], parent[2i+1] = right[i]
    int* cur = curS0; int* nxt = nxtS0;
    int len = 1, lev = 8, idx = off;
    while (idx & 1) {
      const int* Ll = L + loff(lev);
      if (tid < len) {
        const int c = cur[tid];
        nxt[2 * tid] = Ll[tid] ^ c;
        nxt[2 * tid + 1] = c;
      }
      __syncthreads();
      int* t = cur; cur = nxt; nxt = t;
      len <<= 1; idx >>= 1; --lev;
    }
    if (lev > 0) {
      int* Ll = L + loff(lev);
      if (tid < len) Ll[tid] = cur[tid];
    } else {
      // off == 255: root codeword -> output x
      out[OUT_X + b * NN + tid] = (float)cur[tid];
    }
    __syncthreads();
  };

  // initial leftmost descent
  for (int d = 0; d <= 7; ++d) cn(d);
  // sequential leaves
  for (int off = 0; off < NN; ++off) {
    leaf(off);
    if (off < NN - 1) {
      const int z = __ffs(off + 1) - 1;  // ctz(off+1)
      const int dbn = 7 - z;
      bn(dbn);
      for (int d = dbn + 1; d <= 7; ++d) cn(d);
    }
  }
}

extern "C" void kernel_launch(void* const* d_in, const int* in_sizes, int n_in,
                              void* d_out, int out_size, void* d_ws, size_t ws_size,
                              hipStream_t stream) {
  const int*   info_bits = (const int*)d_in[0];
  const float* rv        = (const float*)d_in[1];
  const int*   info_set  = (const int*)d_in[2];
  const float* obs_emb   = (const float*)d_in[3];
  const float* label_emb = (const float*)d_in[4];
  const float* cnW1      = (const float*)d_in[5];
  const float* cnb1      = (const float*)d_in[6];
  const float* cnW2      = (const float*)d_in[7];
  const float* cnb2      = (const float*)d_in[8];
  const float* bnW1      = (const float*)d_in[9];
  const float* bnb1      = (const float*)d_in[10];
  const float* bnW2      = (const float*)d_in[11];
  const float* bnb2      = (const float*)d_in[12];
  const float* llrW      = (const float*)d_in[13];
  const float* llrb      = (const float*)d_in[14];

  float* out  = (float*)d_out;
  float* Ebuf = (float*)d_ws;
  int*   Lbuf = (int*)((char*)d_ws + (size_t)NB * EPB * sizeof(float));

  sc_monolith<<<dim3(NB), dim3(256), 0, stream>>>(
      info_bits, rv, info_set, obs_emb, label_emb,
      cnW1, cnb1, cnW2, cnb2, bnW1, bnb1, bnW2, bnb2,
      llrW, llrb, out, Ebuf, Lbuf);
}